// Round 1
// baseline (460.420 us; speedup 1.0000x reference)
//
#include <hip/hip_runtime.h>
#include <math.h>

#define C 256
#define NLEN 64
#define NN 4096
#define T_INV 10.0f
#define NEG_IOU_TH 0.5f
#define SGROUP 32

__device__ __forceinline__ float wave_reduce_sum(float v) {
    #pragma unroll
    for (int off = 32; off > 0; off >>= 1) v += __shfl_xor(v, off, 64);
    return v;
}

// --- tiny prep: scatter maps + zero accumulators -------------------------
__global__ void k_scatter(const int* __restrict__ num_sentences,
                          const int* __restrict__ num_targets,
                          int B, int S, int M,
                          int* __restrict__ b2s, int* __restrict__ s2b,
                          int* __restrict__ m2s, float* __restrict__ denomq) {
    if (threadIdx.x == 0) {
        int acc = 0;
        for (int b = 0; b < B; ++b) {
            b2s[b] = acc;
            int ns = num_sentences[b];
            for (int k = 0; k < ns; ++k) s2b[acc + k] = b;
            acc += ns;
        }
        int mi = 0;
        for (int s = 0; s < S; ++s) {
            int nt = num_targets[s];
            for (int k = 0; k < nt; ++k) m2s[mi++] = s;
        }
    }
    for (int i = threadIdx.x; i < S; i += blockDim.x) denomq[i] = 0.f;
}

// --- normalize sents_feats; write row-major and transposed ---------------
__global__ void k_norm_sf(const float* __restrict__ sents,
                          float* __restrict__ sfn, float* __restrict__ sfT,
                          int S) {
    __shared__ float red[4];
    int s = blockIdx.x, tid = threadIdx.x;
    float v = sents[(size_t)s * C + tid];
    float ss = wave_reduce_sum(v * v);
    int lane = tid & 63, wave = tid >> 6;
    if (lane == 0) red[wave] = ss;
    __syncthreads();
    float tot = red[0] + red[1] + red[2] + red[3];
    float inv = 1.0f / fmaxf(sqrtf(tot), 1e-12f);
    float nv = v * inv;
    sfn[(size_t)s * C + tid] = nv;
    sfT[(size_t)tid * S + s] = nv;
}

// --- per-moment: argmax over masked iou2ds, gather+normalize column,
//     dot vs all sf rows -> pos[m], negiv[m] -----------------------------
__global__ void k_topk(const float* __restrict__ vf,
                       const float* __restrict__ iou2ds,
                       const float* __restrict__ sfn,
                       const int* __restrict__ m2s,
                       float* __restrict__ pos, float* __restrict__ negiv,
                       int S) {
    __shared__ float tv[C];
    __shared__ float sred[4];
    __shared__ int   sidx[4];
    __shared__ float sc[64];
    __shared__ int   bestflat;
    int m = blockIdx.x, tid = threadIdx.x;
    int s_m = m2s[m];
    int lane = tid & 63, wave = tid >> 6;

    // argmax over triu-masked flats (lowest index on tie, matching top_k)
    float bv = -1e30f; int bi = NN;
    #pragma unroll
    for (int j = 0; j < NN / 256; ++j) {
        int flat = tid + j * 256;
        int r = flat >> 6, cc = flat & 63;
        if (cc >= r) {
            float val = iou2ds[(size_t)m * NN + flat];
            if (val > bv || (val == bv && flat < bi)) { bv = val; bi = flat; }
        }
    }
    #pragma unroll
    for (int off = 32; off > 0; off >>= 1) {
        float ov = __shfl_xor(bv, off, 64);
        int   oi = __shfl_xor(bi, off, 64);
        if (ov > bv || (ov == bv && oi < bi)) { bv = ov; bi = oi; }
    }
    if (lane == 0) { sred[wave] = bv; sidx[wave] = bi; }
    __syncthreads();
    if (tid == 0) {
        float v0 = sred[0]; int i0 = sidx[0];
        for (int w = 1; w < 4; ++w)
            if (sred[w] > v0 || (sred[w] == v0 && sidx[w] < i0)) { v0 = sred[w]; i0 = sidx[w]; }
        bestflat = i0;
    }
    __syncthreads();
    int flat = bestflat;

    // gather strided column (c = tid), normalize
    float v = vf[((size_t)s_m * C + tid) * NN + flat];
    float ss = wave_reduce_sum(v * v);
    if (lane == 0) sred[wave] = ss;
    __syncthreads();
    float tot = sred[0] + sred[1] + sred[2] + sred[3];
    float inv = 1.0f / fmaxf(sqrtf(tot), 1e-12f);
    tv[tid] = v * inv;
    __syncthreads();

    if (tid < 64) {
        float d = 0.f;
        for (int c2 = 0; c2 < C; ++c2) d += tv[c2] * sfn[(size_t)tid * C + c2];
        sc[tid] = d;
    }
    __syncthreads();
    if (tid < 64) {
        float d = sc[tid];
        if (tid == s_m) pos[m] = d;
        float e = (tid == s_m) ? 0.f : expf(d * T_INV);
        e = wave_reduce_sum(e);
        if (tid == 0) negiv[m] = e;
    }
}

// --- inter-query denominators: for video b, s-group g, 256 flat columns
//     per block: acc[s] = sum_c sfT[c][s] * V[c][flat]; then exp/mask/sum.
__global__ void __launch_bounds__(256)
k_q(const float* __restrict__ vf, const float* __restrict__ iou2d,
    const float* __restrict__ sfT, const int* __restrict__ b2s,
    const int* __restrict__ num_sentences,
    float* __restrict__ denomq, int S) {
    __shared__ float dw[4][SGROUP];
    int tile = blockIdx.x, b = blockIdx.y, g = blockIdx.z;
    int tid = threadIdx.x;
    int sb = b2s[b];
    int ns = num_sentences[b];
    int s0 = g * SGROUP;

    float acc[SGROUP];
    #pragma unroll
    for (int s = 0; s < SGROUP; ++s) acc[s] = 0.f;
    float ss = 0.f;

    const float* basep = vf + (size_t)sb * C * NN + (size_t)(tile * 256 + tid);
    for (int c = 0; c < C; ++c) {
        float v = basep[(size_t)c * NN];
        ss += v * v;
        const float* srow = sfT + (size_t)c * S + s0;  // wave-uniform row
        #pragma unroll
        for (int s = 0; s < SGROUP; ++s) acc[s] += srow[s] * v;
    }

    int flat = tile * 256 + tid;
    int r = flat >> 6, cc = flat & 63;
    bool valid = (cc >= r);
    float inv = 1.0f / fmaxf(sqrtf(ss), 1e-12f);

    unsigned long long bits = 0ull;  // pos-mask bits for this video's sentences
    if (valid) {
        for (int i = 0; i < ns; ++i)
            if (iou2d[(size_t)(sb + i) * NN + flat] > NEG_IOU_TH) bits |= (1ull << i);
    }

    int lane = tid & 63, wave = tid >> 6;
    for (int s = 0; s < SGROUP; ++s) {
        int s_abs = s0 + s;
        float e = 0.f;
        if (valid) {
            float scv = acc[s] * inv;
            e = expf(scv * T_INV);
            int rel = s_abs - sb;
            if (rel >= 0 && rel < ns && ((bits >> rel) & 1ull)) e = 0.f;
        }
        e = wave_reduce_sum(e);
        if (lane == 0) dw[wave][s] = e;
    }
    __syncthreads();
    if (tid < SGROUP) {
        float tot = dw[0][tid] + dw[1][tid] + dw[2][tid] + dw[3][tid];
        atomicAdd(&denomq[s0 + tid], tot);
    }
}

// --- final: combine both losses, mean over M -----------------------------
__global__ void k_final(const float* __restrict__ pos,
                        const float* __restrict__ negiv,
                        const float* __restrict__ denomq,
                        const int* __restrict__ m2s,
                        float* __restrict__ out, int M) {
    __shared__ float red[2];
    int tid = threadIdx.x;
    float val = 0.f;
    if (tid < M) {
        int s = m2s[tid];
        float pl = pos[tid] * T_INV;
        float pe = expf(pl);
        float liv = -(pl - logf(pe + negiv[tid]));
        float liq = -(pl - logf(pe + denomq[s]));
        val = liv + liq;
    }
    val = wave_reduce_sum(val);
    int lane = tid & 63, wave = tid >> 6;
    if (lane == 0) red[wave] = val;
    __syncthreads();
    if (tid == 0) out[0] = (red[0] + red[1]) / (float)M;
}

extern "C" void kernel_launch(void* const* d_in, const int* in_sizes, int n_in,
                              void* d_out, int out_size, void* d_ws, size_t ws_size,
                              hipStream_t stream) {
    const float* video_feats   = (const float*)d_in[0];
    const float* sents_feats   = (const float*)d_in[1];
    const float* iou2d         = (const float*)d_in[2];
    const float* iou2ds        = (const float*)d_in[3];
    const int*   num_sentences = (const int*)d_in[4];
    const int*   num_targets   = (const int*)d_in[5];
    // d_in[6] = mask2d: statically triu(ones(64,64)); computed as cc>=r in-kernel.

    const int S = in_sizes[2] / NN;   // 64
    const int B = in_sizes[4];        // 16
    const int M = in_sizes[3] / NN;   // 128

    float* sfn    = (float*)d_ws;
    float* sfT    = sfn + (size_t)S * C;
    float* pos    = sfT + (size_t)C * S;
    float* negiv  = pos + M;
    float* denomq = negiv + M;
    int*   b2s    = (int*)(denomq + S);
    int*   s2b    = b2s + B;
    int*   m2s    = s2b + S;

    k_scatter<<<1, 64, 0, stream>>>(num_sentences, num_targets, B, S, M,
                                    b2s, s2b, m2s, denomq);
    k_norm_sf<<<S, C, 0, stream>>>(sents_feats, sfn, sfT, S);
    k_topk<<<M, 256, 0, stream>>>(video_feats, iou2ds, sfn, m2s, pos, negiv, S);
    k_q<<<dim3(NN / 256, B, S / SGROUP), 256, 0, stream>>>(
        video_feats, iou2d, sfT, b2s, num_sentences, denomq, S);
    k_final<<<1, 128, 0, stream>>>(pos, negiv, denomq, m2s, (float*)d_out, M);
}

// Round 2
// 415.553 us; speedup vs baseline: 1.1080x; 1.1080x over previous
//
#include <hip/hip_runtime.h>
#include <math.h>

#define C 256
#define NLEN 64
#define NN 4096
#define T_INV 10.0f
#define NEG_IOU_TH 0.5f
#define SGROUP 16
#define FLATS 2

__device__ __forceinline__ float wave_reduce_sum(float v) {
    #pragma unroll
    for (int off = 32; off > 0; off >>= 1) v += __shfl_xor(v, off, 64);
    return v;
}

// --- tiny prep: scatter maps + zero accumulators -------------------------
__global__ void k_scatter(const int* __restrict__ num_sentences,
                          const int* __restrict__ num_targets,
                          int B, int S, int M,
                          int* __restrict__ b2s, int* __restrict__ s2b,
                          int* __restrict__ m2s, float* __restrict__ denomq) {
    if (threadIdx.x == 0) {
        int acc = 0;
        for (int b = 0; b < B; ++b) {
            b2s[b] = acc;
            int ns = num_sentences[b];
            for (int k = 0; k < ns; ++k) s2b[acc + k] = b;
            acc += ns;
        }
        int mi = 0;
        for (int s = 0; s < S; ++s) {
            int nt = num_targets[s];
            for (int k = 0; k < nt; ++k) m2s[mi++] = s;
        }
    }
    for (int i = threadIdx.x; i < S; i += blockDim.x) denomq[i] = 0.f;
}

// --- normalize sents_feats; write transposed (c-major, s stride-1) -------
__global__ void k_norm_sf(const float* __restrict__ sents,
                          float* __restrict__ sfT, int S) {
    __shared__ float red[4];
    int s = blockIdx.x, tid = threadIdx.x;
    float v = sents[(size_t)s * C + tid];
    float ss = wave_reduce_sum(v * v);
    int lane = tid & 63, wave = tid >> 6;
    if (lane == 0) red[wave] = ss;
    __syncthreads();
    float tot = red[0] + red[1] + red[2] + red[3];
    float inv = 1.0f / fmaxf(sqrtf(tot), 1e-12f);
    sfT[(size_t)tid * S + s] = v * inv;
}

// --- per-moment: argmax over masked iou2ds, gather+normalize column,
//     dot vs all sf rows -> pos[m], negiv[m] -----------------------------
__global__ void k_topk(const float* __restrict__ vf,
                       const float* __restrict__ iou2ds,
                       const float* __restrict__ sfT,
                       const int* __restrict__ m2s,
                       float* __restrict__ pos, float* __restrict__ negiv,
                       int S) {
    __shared__ float tv[C];
    __shared__ float sred[4];
    __shared__ int   sidx[4];
    __shared__ float sc4[4][64];
    __shared__ int   bestflat;
    int m = blockIdx.x, tid = threadIdx.x;
    int s_m = m2s[m];
    int lane = tid & 63, wave = tid >> 6;

    // argmax over triu-masked flats (lowest index on tie, matching top_k)
    float bv = -1e30f; int bi = NN;
    #pragma unroll
    for (int j = 0; j < NN / 256; ++j) {
        int flat = tid + j * 256;
        int r = flat >> 6, cc = flat & 63;
        if (cc >= r) {
            float val = iou2ds[(size_t)m * NN + flat];
            if (val > bv || (val == bv && flat < bi)) { bv = val; bi = flat; }
        }
    }
    #pragma unroll
    for (int off = 32; off > 0; off >>= 1) {
        float ov = __shfl_xor(bv, off, 64);
        int   oi = __shfl_xor(bi, off, 64);
        if (ov > bv || (ov == bv && oi < bi)) { bv = ov; bi = oi; }
    }
    if (lane == 0) { sred[wave] = bv; sidx[wave] = bi; }
    __syncthreads();
    if (tid == 0) {
        float v0 = sred[0]; int i0 = sidx[0];
        for (int w = 1; w < 4; ++w)
            if (sred[w] > v0 || (sred[w] == v0 && sidx[w] < i0)) { v0 = sred[w]; i0 = sidx[w]; }
        bestflat = i0;
    }
    __syncthreads();
    int flat = bestflat;

    // gather strided column (c = tid), normalize
    float v = vf[((size_t)s_m * C + tid) * NN + flat];
    float ss = wave_reduce_sum(v * v);
    if (lane == 0) sred[wave] = ss;
    __syncthreads();
    float tot = sred[0] + sred[1] + sred[2] + sred[3];
    float inv = 1.0f / fmaxf(sqrtf(tot), 1e-12f);
    tv[tid] = v * inv;
    __syncthreads();

    // dot vs all S sentence reps via sfT (coalesced in s), 4 c-groups
    {
        int s = tid & 63, cg = tid >> 6;
        float d = 0.f;
        for (int j = 0; j < 64; ++j) {
            int c2 = cg * 64 + j;
            d += tv[c2] * sfT[(size_t)c2 * S + s];
        }
        sc4[cg][s] = d;
    }
    __syncthreads();
    if (tid < 64) {
        float d = sc4[0][tid] + sc4[1][tid] + sc4[2][tid] + sc4[3][tid];
        if (tid == s_m) pos[m] = d;
        float e = (tid == s_m) ? 0.f : expf(d * T_INV);
        e = wave_reduce_sum(e);
        if (tid == 0) negiv[m] = e;
    }
}

// --- inter-query denominators: block = (flat-tile of 512, video b, s-group
//     of 16). Each thread owns a float2 flat-pair; sfT tile lives in LDS. --
__global__ void __launch_bounds__(256)
k_q(const float* __restrict__ vf, const float* __restrict__ iou2d,
    const float* __restrict__ sfT, const int* __restrict__ b2s,
    const int* __restrict__ num_sentences,
    float* __restrict__ denomq, int S) {
    __shared__ float sT[C * SGROUP];   // [c][s], 16 KB
    __shared__ float dw[4][SGROUP];
    int tile = blockIdx.x, b = blockIdx.y, g = blockIdx.z;
    int tid = threadIdx.x;
    int sb = b2s[b];
    int ns = num_sentences[b];
    int s0 = g * SGROUP;

    // stage sfT[:, s0:s0+16] into LDS
    for (int k = tid; k < C * SGROUP; k += 256) {
        int c = k >> 4, s = k & (SGROUP - 1);
        sT[k] = sfT[(size_t)c * S + s0 + s];
    }
    __syncthreads();

    int flat0 = tile * (256 * FLATS) + tid * FLATS;
    const float2* vp = (const float2*)(vf + (size_t)sb * C * NN + flat0);

    float acc0[SGROUP], acc1[SGROUP];
    #pragma unroll
    for (int s = 0; s < SGROUP; ++s) { acc0[s] = 0.f; acc1[s] = 0.f; }
    float ss0 = 0.f, ss1 = 0.f;

    #pragma unroll 2
    for (int c = 0; c < C; ++c) {
        float2 v = vp[(size_t)c * (NN / 2)];
        ss0 += v.x * v.x;
        ss1 += v.y * v.y;
        const float4* sr = (const float4*)&sT[c * SGROUP];
        #pragma unroll
        for (int q = 0; q < SGROUP / 4; ++q) {
            float4 s4 = sr[q];
            acc0[q*4+0] += s4.x * v.x;  acc1[q*4+0] += s4.x * v.y;
            acc0[q*4+1] += s4.y * v.x;  acc1[q*4+1] += s4.y * v.y;
            acc0[q*4+2] += s4.z * v.x;  acc1[q*4+2] += s4.z * v.y;
            acc0[q*4+3] += s4.w * v.x;  acc1[q*4+3] += s4.w * v.y;
        }
    }

    int fA = flat0, fB = flat0 + 1;
    bool vA = ((fA & 63) >= (fA >> 6));
    bool vB = ((fB & 63) >= (fB >> 6));
    float invA = 1.0f / fmaxf(sqrtf(ss0), 1e-12f);
    float invB = 1.0f / fmaxf(sqrtf(ss1), 1e-12f);

    unsigned long long bitsA = 0ull, bitsB = 0ull;
    for (int i = 0; i < ns; ++i) {
        const float* row = iou2d + (size_t)(sb + i) * NN;
        if (vA && row[fA] > NEG_IOU_TH) bitsA |= (1ull << i);
        if (vB && row[fB] > NEG_IOU_TH) bitsB |= (1ull << i);
    }

    int lane = tid & 63, wave = tid >> 6;
    #pragma unroll
    for (int s = 0; s < SGROUP; ++s) {
        int s_abs = s0 + s;
        int rel = s_abs - sb;
        bool inblk = (rel >= 0 && rel < ns);
        float e = 0.f;
        if (vA && !(inblk && ((bitsA >> rel) & 1ull)))
            e += expf(acc0[s] * invA * T_INV);
        if (vB && !(inblk && ((bitsB >> rel) & 1ull)))
            e += expf(acc1[s] * invB * T_INV);
        e = wave_reduce_sum(e);
        if (lane == 0) dw[wave][s] = e;
    }
    __syncthreads();
    if (tid < SGROUP) {
        float tot = dw[0][tid] + dw[1][tid] + dw[2][tid] + dw[3][tid];
        atomicAdd(&denomq[s0 + tid], tot);
    }
}

// --- final: combine both losses, mean over M -----------------------------
__global__ void k_final(const float* __restrict__ pos,
                        const float* __restrict__ negiv,
                        const float* __restrict__ denomq,
                        const int* __restrict__ m2s,
                        float* __restrict__ out, int M) {
    __shared__ float red[2];
    int tid = threadIdx.x;
    float val = 0.f;
    if (tid < M) {
        int s = m2s[tid];
        float pl = pos[tid] * T_INV;
        float pe = expf(pl);
        float liv = -(pl - logf(pe + negiv[tid]));
        float liq = -(pl - logf(pe + denomq[s]));
        val = liv + liq;
    }
    val = wave_reduce_sum(val);
    int lane = tid & 63, wave = tid >> 6;
    if (lane == 0) red[wave] = val;
    __syncthreads();
    if (tid == 0) out[0] = (red[0] + red[1]) / (float)M;
}

extern "C" void kernel_launch(void* const* d_in, const int* in_sizes, int n_in,
                              void* d_out, int out_size, void* d_ws, size_t ws_size,
                              hipStream_t stream) {
    const float* video_feats   = (const float*)d_in[0];
    const float* sents_feats   = (const float*)d_in[1];
    const float* iou2d         = (const float*)d_in[2];
    const float* iou2ds        = (const float*)d_in[3];
    const int*   num_sentences = (const int*)d_in[4];
    const int*   num_targets   = (const int*)d_in[5];
    // d_in[6] = mask2d: statically triu(ones(64,64)); computed as cc>=r in-kernel.

    const int S = in_sizes[2] / NN;   // 64
    const int B = in_sizes[4];        // 16
    const int M = in_sizes[3] / NN;   // 128

    float* sfT    = (float*)d_ws;            // C*S
    float* pos    = sfT + (size_t)C * 64;
    float* negiv  = pos + M;
    float* denomq = negiv + M;
    int*   b2s    = (int*)(denomq + S);
    int*   s2b    = b2s + B;
    int*   m2s    = s2b + S;

    k_scatter<<<1, 64, 0, stream>>>(num_sentences, num_targets, B, S, M,
                                    b2s, s2b, m2s, denomq);
    k_norm_sf<<<S, C, 0, stream>>>(sents_feats, sfT, S);
    k_topk<<<M, 256, 0, stream>>>(video_feats, iou2ds, sfT, m2s, pos, negiv, S);
    k_q<<<dim3(NN / (256 * FLATS), B, S / SGROUP), 256, 0, stream>>>(
        video_feats, iou2d, sfT, b2s, num_sentences, denomq, S);
    k_final<<<1, 128, 0, stream>>>(pos, negiv, denomq, m2s, (float*)d_out, M);
}